// Round 1
// baseline (2363.531 us; speedup 1.0000x reference)
//
#include <hip/hip_runtime.h>

#define N_N 100000
#define N_E 1600000
#define N_G 256
#define F_IN 28
#define HEADS 4
#define CH 64
#define NEG 0.2f
#define LN_EPS 1e-5f

__device__ __forceinline__ float lrelu(float x) { return x > 0.f ? x : NEG * x; }

__device__ __forceinline__ float wsum(float v) {
#pragma unroll
  for (int o = 32; o > 0; o >>= 1) v += __shfl_xor(v, o, 64);
  return v;
}
__device__ __forceinline__ float wmax(float v) {
#pragma unroll
  for (int o = 32; o > 0; o >>= 1) v = fmaxf(v, __shfl_xor(v, o, 64));
  return v;
}
__device__ __forceinline__ int wsumi(int v) {
#pragma unroll
  for (int o = 32; o > 0; o >>= 1) v += __shfl_xor(v, o, 64);
  return v;
}

// ---------------- CSR build ----------------
__global__ __launch_bounds__(256) void k_deg(const int* __restrict__ dst, int* deg) {
  int e = blockIdx.x * 256 + threadIdx.x;
  if (e < N_E) atomicAdd(&deg[dst[e]], 1);
}

__global__ __launch_bounds__(256) void k_bsum(const int* __restrict__ deg, int* __restrict__ bsum) {
  __shared__ int l[4];
  int t = threadIdx.x;
  int i = blockIdx.x * 256 + t;
  int v = (i < N_N) ? deg[i] : 0;
  int s = wsumi(v);
  if ((t & 63) == 0) l[t >> 6] = s;
  __syncthreads();
  if (t == 0) bsum[blockIdx.x] = l[0] + l[1] + l[2] + l[3];
}

__global__ __launch_bounds__(512) void k_scanb(const int* __restrict__ bsum, int* __restrict__ bofs, int nb) {
  __shared__ int l[512];
  int t = threadIdx.x;
  int v = (t < nb) ? bsum[t] : 0;
  l[t] = v;
  __syncthreads();
  for (int o = 1; o < 512; o <<= 1) {
    int a = (t >= o) ? l[t - o] : 0;
    __syncthreads();
    l[t] += a;
    __syncthreads();
  }
  if (t < nb) bofs[t] = l[t] - v;  // exclusive
}

__global__ __launch_bounds__(256) void k_indptr(const int* __restrict__ deg, const int* __restrict__ bofs,
                                                int* __restrict__ indptr) {
  __shared__ int l[256];
  int t = threadIdx.x;
  int i = blockIdx.x * 256 + t;
  int v = (i < N_N) ? deg[i] : 0;
  l[t] = v;
  __syncthreads();
  for (int o = 1; o < 256; o <<= 1) {
    int a = (t >= o) ? l[t - o] : 0;
    __syncthreads();
    l[t] += a;
    __syncthreads();
  }
  if (i < N_N) indptr[i] = bofs[blockIdx.x] + l[t] - v;
  if (i == 0) indptr[N_N] = N_E;
}

__global__ __launch_bounds__(256) void k_copyfill(const int* __restrict__ indptr, int* __restrict__ fill) {
  int i = blockIdx.x * 256 + threadIdx.x;
  if (i < N_N) fill[i] = indptr[i];
}

__global__ __launch_bounds__(256) void k_scatter(const int* __restrict__ src, const int* __restrict__ dst,
                                                 int* fill, int* __restrict__ csr) {
  int e = blockIdx.x * 256 + threadIdx.x;
  if (e < N_E) {
    int d = dst[e];
    int p = atomicAdd(&fill[d], 1);
    csr[p] = src[e];
  }
}

// deterministic order within each bucket (sum order fixed across runs)
__global__ __launch_bounds__(256) void k_sort(const int* __restrict__ indptr, int* __restrict__ csr) {
  int i = blockIdx.x * 256 + threadIdx.x;
  if (i >= N_N) return;
  int b = indptr[i], e = indptr[i + 1];
  for (int j = b + 1; j < e; ++j) {
    int key = csr[j];
    int k = j - 1;
    while (k >= b && csr[k] > key) { csr[k + 1] = csr[k]; --k; }
    csr[k + 1] = key;
  }
}

// ---------------- attention logits: al = x @ (W_h a_h) ----------------
template <int F>
__global__ __launch_bounds__(256) void k_avec(const float* __restrict__ W, const float* __restrict__ as_,
                                              const float* __restrict__ ad_, float* __restrict__ wsv,
                                              float* __restrict__ wdv) {
  int idx = blockIdx.x * 256 + threadIdx.x;
  if (idx >= HEADS * F) return;
  int h = idx / F, f = idx % F;
  float s = 0.f, d = 0.f;
  for (int c = 0; c < 64; ++c) {
    float w = W[(h * F + f) * 64 + c];
    s = fmaf(w, as_[h * 64 + c], s);
    d = fmaf(w, ad_[h * 64 + c], d);
  }
  wsv[idx] = s;
  wdv[idx] = d;
}

template <int F>
__global__ __launch_bounds__(256) void k_al(const float* __restrict__ xin, const float* __restrict__ wsv,
                                            const float* __restrict__ wdv, float* __restrict__ al_s,
                                            float* __restrict__ al_d) {
  int wv = threadIdx.x >> 6, lane = threadIdx.x & 63;
  for (int i = blockIdx.x * 4 + wv; i < N_N; i += gridDim.x * 4) {
    float xv = (lane < F) ? xin[(size_t)i * F + lane] : 0.f;
#pragma unroll
    for (int h = 0; h < HEADS; ++h) {
      float ws_ = (lane < F) ? wsv[h * F + lane] : 0.f;
      float wd_ = (lane < F) ? wdv[h * F + lane] : 0.f;
      float ss = wsum(xv * ws_);
      float sd = wsum(xv * wd_);
      if (lane == 0) {
        al_s[i * 4 + h] = ss;
        al_d[i * 4 + h] = sd;
      }
    }
  }
}

// ---------------- fused GAT layer (wave per node) ----------------
// out[i,c] = relu( bias[c] + 0.25 * sum_h sum_f aggF[i,h,f] * W[h,f,c] )
// aggF[i,h,f] = softmax-weighted sum over in-edges (incl self loop) of xin[s,f]
template <int F>
__global__ __launch_bounds__(256) void k_gat(const float* __restrict__ xin, const int* __restrict__ indptr,
                                             const int* __restrict__ csr, const float* __restrict__ al_s,
                                             const float* __restrict__ al_d, const float* __restrict__ W,
                                             const float* __restrict__ bias, float* __restrict__ xg) {
  __shared__ float wl[HEADS * F * 64];
  int t = threadIdx.x;
  for (int idx = t; idx < HEADS * F * 64; idx += 256) wl[idx] = W[idx];
  __syncthreads();
  int wv = t >> 6, lane = t & 63;
  for (int i = blockIdx.x * 4 + wv; i < N_N; i += gridDim.x * 4) {
    int b = indptr[i], e = indptr[i + 1];
    float4 ad4 = *(const float4*)&al_d[i * 4];
    float4 asi = *(const float4*)&al_s[i * 4];
    float es0 = lrelu(asi.x + ad4.x), es1 = lrelu(asi.y + ad4.y);
    float es2 = lrelu(asi.z + ad4.z), es3 = lrelu(asi.w + ad4.w);
    // pass 1: max
    float pm0 = -1e30f, pm1 = -1e30f, pm2 = -1e30f, pm3 = -1e30f;
    for (int j = b + lane; j < e; j += 64) {
      int s = csr[j];
      float4 a4 = *(const float4*)&al_s[s * 4];
      pm0 = fmaxf(pm0, lrelu(a4.x + ad4.x));
      pm1 = fmaxf(pm1, lrelu(a4.y + ad4.y));
      pm2 = fmaxf(pm2, lrelu(a4.z + ad4.z));
      pm3 = fmaxf(pm3, lrelu(a4.w + ad4.w));
    }
    float m0 = fmaxf(wmax(pm0), es0), m1 = fmaxf(wmax(pm1), es1);
    float m2 = fmaxf(wmax(pm2), es2), m3 = fmaxf(wmax(pm3), es3);
    // pass 2: denom
    float pd0 = 0.f, pd1 = 0.f, pd2 = 0.f, pd3 = 0.f;
    for (int j = b + lane; j < e; j += 64) {
      int s = csr[j];
      float4 a4 = *(const float4*)&al_s[s * 4];
      pd0 += __expf(lrelu(a4.x + ad4.x) - m0);
      pd1 += __expf(lrelu(a4.y + ad4.y) - m1);
      pd2 += __expf(lrelu(a4.z + ad4.z) - m2);
      pd3 += __expf(lrelu(a4.w + ad4.w) - m3);
    }
    float dn0 = wsum(pd0) + __expf(es0 - m0);
    float dn1 = wsum(pd1) + __expf(es1 - m1);
    float dn2 = wsum(pd2) + __expf(es2 - m2);
    float dn3 = wsum(pd3) + __expf(es3 - m3);
    // pass 3: weighted aggregate of input features
    float xself = (lane < F) ? xin[(size_t)i * F + lane] : 0.f;
    float a0 = __expf(es0 - m0) * xself;
    float a1 = __expf(es1 - m1) * xself;
    float a2 = __expf(es2 - m2) * xself;
    float a3 = __expf(es3 - m3) * xself;
    for (int j = b; j < e; ++j) {
      int s = csr[j];  // uniform across wave
      float4 a4 = *(const float4*)&al_s[s * 4];
      float xv = (lane < F) ? xin[(size_t)s * F + lane] : 0.f;
      a0 = fmaf(__expf(lrelu(a4.x + ad4.x) - m0), xv, a0);
      a1 = fmaf(__expf(lrelu(a4.y + ad4.y) - m1), xv, a1);
      a2 = fmaf(__expf(lrelu(a4.z + ad4.z) - m2), xv, a2);
      a3 = fmaf(__expf(lrelu(a4.w + ad4.w) - m3), xv, a3);
    }
    a0 /= dn0; a1 /= dn1; a2 /= dn2; a3 /= dn3;
    // apply W: o[c] = 0.25 * sum_h sum_f agg[h][f] * W[h,f,c]
    float o = 0.f;
#pragma unroll 4
    for (int f = 0; f < F; ++f) {
      float v0 = __shfl(a0, f, 64);
      float v1 = __shfl(a1, f, 64);
      float v2 = __shfl(a2, f, 64);
      float v3 = __shfl(a3, f, 64);
      o = fmaf(v0, wl[(0 * F + f) * 64 + lane], o);
      o = fmaf(v1, wl[(1 * F + f) * 64 + lane], o);
      o = fmaf(v2, wl[(2 * F + f) * 64 + lane], o);
      o = fmaf(v3, wl[(3 * F + f) * 64 + lane], o);
    }
    o = fmaxf(fmaf(o, 0.25f, bias[lane]), 0.f);
    xg[(size_t)i * 64 + lane] = o;
  }
}

// ---------------- fused GIN: agg + MLP + residual + LN ----------------
__global__ __launch_bounds__(256) void k_gin(const int* __restrict__ indptr, const int* __restrict__ csr,
                                             const float* __restrict__ xg, const float* __restrict__ w1,
                                             const float* __restrict__ b1, const float* __restrict__ w2,
                                             const float* __restrict__ b2, const float* __restrict__ lnw,
                                             const float* __restrict__ lnb, float* __restrict__ xo) {
  __shared__ float w1l[4096], w2l[4096];
  int t = threadIdx.x;
  for (int idx = t; idx < 4096; idx += 256) {
    w1l[idx] = w1[idx];
    w2l[idx] = w2[idx];
  }
  __syncthreads();
  int wv = t >> 6, lane = t & 63;
  for (int i = blockIdx.x * 4 + wv; i < N_N; i += gridDim.x * 4) {
    int b = indptr[i], e = indptr[i + 1];
    float xi = xg[(size_t)i * 64 + lane];
    float acc = xi;
    for (int j = b; j < e; ++j) acc += xg[(size_t)csr[j] * 64 + lane];
    float hv = b1[lane];
#pragma unroll 8
    for (int k = 0; k < 64; ++k) hv = fmaf(__shfl(acc, k, 64), w1l[k * 64 + lane], hv);
    hv = fmaxf(hv, 0.f);
    float ov = b2[lane];
#pragma unroll 8
    for (int k = 0; k < 64; ++k) ov = fmaf(__shfl(hv, k, 64), w2l[k * 64 + lane], ov);
    float res = xi + ov;
    float mu = wsum(res) * (1.f / 64.f);
    float d = res - mu;
    float var = wsum(d * d) * (1.f / 64.f);
    xo[(size_t)i * 64 + lane] = fmaf(d * rsqrtf(var + LN_EPS), lnw[lane], lnb[lane]);
  }
}

// ---------------- gate MLP ----------------
__global__ __launch_bounds__(256) void k_gatenn(const float* __restrict__ x2, const float* __restrict__ gw1,
                                                const float* __restrict__ gb1, const float* __restrict__ gw2,
                                                const float* __restrict__ gb2, float* __restrict__ gate) {
  __shared__ float wl[4096];
  __shared__ float g2l[64];
  int t = threadIdx.x;
  for (int idx = t; idx < 4096; idx += 256) wl[idx] = gw1[idx];
  if (t < 64) g2l[t] = gw2[t];
  __syncthreads();
  int wv = t >> 6, lane = t & 63;
  float gb2v = gb2[0];
  for (int i = blockIdx.x * 4 + wv; i < N_N; i += gridDim.x * 4) {
    float vv = x2[(size_t)i * 64 + lane];
    float hv = gb1[lane];
#pragma unroll 8
    for (int k = 0; k < 64; ++k) hv = fmaf(__shfl(vv, k, 64), wl[k * 64 + lane], hv);
    hv = fmaxf(hv, 0.f);
    float g = wsum(hv * g2l[lane]);
    if (lane == 0) gate[i] = g + gb2v;
  }
}

// ---------------- graph ranges via counting ----------------
__global__ __launch_bounds__(256) void k_gcount(const int* __restrict__ batch, int* gcnt) {
  int i = blockIdx.x * 256 + threadIdx.x;
  if (i < N_N) atomicAdd(&gcnt[batch[i]], 1);
}

__global__ __launch_bounds__(256) void k_gptr(const int* __restrict__ gcnt, int* __restrict__ gptr) {
  __shared__ int l[256];
  int t = threadIdx.x;
  int v = gcnt[t];
  l[t] = v;
  __syncthreads();
  for (int o = 1; o < 256; o <<= 1) {
    int a = (t >= o) ? l[t - o] : 0;
    __syncthreads();
    l[t] += a;
    __syncthreads();
  }
  gptr[t] = l[t] - v;
  if (t == 255) gptr[256] = l[255];
}

// ---------------- global attention pool ----------------
__global__ __launch_bounds__(256) void k_pool(const int* __restrict__ gptr, const float* __restrict__ gate,
                                              const float* __restrict__ x2, float* __restrict__ pooled) {
  int g = blockIdx.x;
  int t = threadIdx.x, wv = t >> 6, lane = t & 63;
  __shared__ float red[256];
  int b = gptr[g], e = gptr[g + 1];
  if (b == e) {
    if (t < 64) pooled[g * 64 + t] = 0.f;
    return;
  }
  float m = -1e30f;
  for (int j = b + t; j < e; j += 256) m = fmaxf(m, gate[j]);
  m = wmax(m);
  if (lane == 0) red[wv] = m;
  __syncthreads();
  m = fmaxf(fmaxf(red[0], red[1]), fmaxf(red[2], red[3]));
  __syncthreads();
  float dn = 0.f;
  for (int j = b + t; j < e; j += 256) dn += __expf(gate[j] - m);
  dn = wsum(dn);
  if (lane == 0) red[wv] = dn;
  __syncthreads();
  dn = red[0] + red[1] + red[2] + red[3];
  __syncthreads();
  float acc = 0.f;
  for (int j = b + wv; j < e; j += 4) acc = fmaf(__expf(gate[j] - m), x2[(size_t)j * 64 + lane], acc);
  red[t] = acc;
  __syncthreads();
  if (t < 64) pooled[g * 64 + t] = (red[t] + red[t + 64] + red[t + 128] + red[t + 192]) / dn;
}

// ---------------- head MLP ----------------
__global__ __launch_bounds__(128) void k_head(const float* __restrict__ pooled, const float* __restrict__ l1w,
                                              const float* __restrict__ l1b, const float* __restrict__ lnfw,
                                              const float* __restrict__ lnfb, const float* __restrict__ l2w,
                                              const float* __restrict__ l2b, float* __restrict__ out) {
  int g = blockIdx.x, t = threadIdx.x;
  __shared__ float pl[64], zl[128], red[2];
  if (t < 64) pl[t] = pooled[g * 64 + t];
  __syncthreads();
  float y = l1b[t];
#pragma unroll 8
  for (int k = 0; k < 64; ++k) y = fmaf(pl[k], l1w[k * 128 + t], y);
  int wv = t >> 6, lane = t & 63;
  float s = wsum(y);
  if (lane == 0) red[wv] = s;
  __syncthreads();
  float mu = (red[0] + red[1]) * (1.f / 128.f);
  float d = y - mu;
  __syncthreads();
  s = wsum(d * d);
  if (lane == 0) red[wv] = s;
  __syncthreads();
  float var = (red[0] + red[1]) * (1.f / 128.f);
  float z = fmaxf(fmaf(d * rsqrtf(var + LN_EPS), lnfw[t], lnfb[t]), 0.f);
  zl[t] = z;
  __syncthreads();
  if (t < 6) {
    float o = l2b[t];
    for (int k = 0; k < 128; ++k) o = fmaf(zl[k], l2w[k * 6 + t], o);
    out[g * 6 + t] = o;
  }
}

extern "C" void kernel_launch(void* const* d_in, const int* in_sizes, int n_in,
                              void* d_out, int out_size, void* d_ws, size_t ws_size,
                              hipStream_t stream) {
  const float* x = (const float*)d_in[0];
  const int* src = (const int*)d_in[1];
  const int* dst = (const int*)d_in[2];
  const int* batch = (const int*)d_in[3];
  const float* W1 = (const float*)d_in[4];
  const float* a1s = (const float*)d_in[5];
  const float* a1d = (const float*)d_in[6];
  const float* bg1 = (const float*)d_in[7];
  const float* m1w1 = (const float*)d_in[8];
  const float* m1b1 = (const float*)d_in[9];
  const float* m1w2 = (const float*)d_in[10];
  const float* m1b2 = (const float*)d_in[11];
  const float* ln1w = (const float*)d_in[12];
  const float* ln1b = (const float*)d_in[13];
  const float* W2 = (const float*)d_in[14];
  const float* a2s = (const float*)d_in[15];
  const float* a2d = (const float*)d_in[16];
  const float* bg2 = (const float*)d_in[17];
  const float* m2w1 = (const float*)d_in[18];
  const float* m2b1 = (const float*)d_in[19];
  const float* m2w2 = (const float*)d_in[20];
  const float* m2b2 = (const float*)d_in[21];
  const float* ln2w = (const float*)d_in[22];
  const float* ln2b = (const float*)d_in[23];
  const float* gw1 = (const float*)d_in[24];
  const float* gb1 = (const float*)d_in[25];
  const float* gw2 = (const float*)d_in[26];
  const float* gb2 = (const float*)d_in[27];
  const float* l1w = (const float*)d_in[28];
  const float* l1b = (const float*)d_in[29];
  const float* lnfw = (const float*)d_in[30];
  const float* lnfb = (const float*)d_in[31];
  const float* l2w = (const float*)d_in[32];
  const float* l2b = (const float*)d_in[33];
  float* out = (float*)d_out;

  char* ws = (char*)d_ws;
  size_t off = 0;
  auto alloc = [&](size_t bytes) -> void* {
    void* p = ws + off;
    off += (bytes + 255) & ~(size_t)255;
    return p;
  };
  int* indptr = (int*)alloc((N_N + 1) * sizeof(int));
  int* fill = (int*)alloc(N_N * sizeof(int));       // also degree
  int* csr = (int*)alloc((size_t)N_E * sizeof(int));
  int* bsum = (int*)alloc(512 * sizeof(int));
  int* bofs = (int*)alloc(512 * sizeof(int));
  int* gcnt = (int*)alloc(257 * sizeof(int));
  int* gptr = (int*)alloc(257 * sizeof(int));
  float* wsv = (float*)alloc(HEADS * 64 * sizeof(float));
  float* wdv = (float*)alloc(HEADS * 64 * sizeof(float));
  float* al_s = (float*)alloc((size_t)N_N * 4 * sizeof(float));
  float* al_d = (float*)alloc((size_t)N_N * 4 * sizeof(float));
  float* gate = (float*)alloc((size_t)N_N * sizeof(float));
  float* pooled = (float*)alloc(N_G * 64 * sizeof(float));
  float* xg = (float*)alloc((size_t)N_N * 64 * sizeof(float));
  float* xv = (float*)alloc((size_t)N_N * 64 * sizeof(float));
  (void)ws_size; (void)n_in; (void)in_sizes; (void)out_size;

  const int NBE = (N_E + 255) / 256;
  const int NBN = (N_N + 255) / 256;  // 391

  hipMemsetAsync(fill, 0, (size_t)N_N * sizeof(int), stream);
  hipMemsetAsync(gcnt, 0, 257 * sizeof(int), stream);
  k_deg<<<NBE, 256, 0, stream>>>(dst, fill);
  k_bsum<<<NBN, 256, 0, stream>>>(fill, bsum);
  k_scanb<<<1, 512, 0, stream>>>(bsum, bofs, NBN);
  k_indptr<<<NBN, 256, 0, stream>>>(fill, bofs, indptr);
  k_copyfill<<<NBN, 256, 0, stream>>>(indptr, fill);
  k_scatter<<<NBE, 256, 0, stream>>>(src, dst, fill, csr);
  k_sort<<<NBN, 256, 0, stream>>>(indptr, csr);
  k_gcount<<<NBN, 256, 0, stream>>>(batch, gcnt);
  k_gptr<<<1, 256, 0, stream>>>(gcnt, gptr);

  // ---- layer 1 ----
  k_avec<F_IN><<<1, 256, 0, stream>>>(W1, a1s, a1d, wsv, wdv);
  k_al<F_IN><<<2048, 256, 0, stream>>>(x, wsv, wdv, al_s, al_d);
  k_gat<F_IN><<<1280, 256, 0, stream>>>(x, indptr, csr, al_s, al_d, W1, bg1, xg);
  k_gin<<<1024, 256, 0, stream>>>(indptr, csr, xg, m1w1, m1b1, m1w2, m1b2, ln1w, ln1b, xv);
  // ---- layer 2 ----
  k_avec<CH><<<1, 256, 0, stream>>>(W2, a2s, a2d, wsv, wdv);
  k_al<CH><<<2048, 256, 0, stream>>>(xv, wsv, wdv, al_s, al_d);
  k_gat<CH><<<512, 256, 0, stream>>>(xv, indptr, csr, al_s, al_d, W2, bg2, xg);
  k_gin<<<1024, 256, 0, stream>>>(indptr, csr, xg, m2w1, m2b1, m2w2, m2b2, ln2w, ln2b, xv);
  // ---- pooling + head ----
  k_gatenn<<<1024, 256, 0, stream>>>(xv, gw1, gb1, gw2, gb2, gate);
  k_pool<<<N_G, 256, 0, stream>>>(gptr, gate, xv, pooled);
  k_head<<<N_G, 128, 0, stream>>>(pooled, l1w, l1b, lnfw, lnfb, l2w, l2b, out);
}

// Round 2
// 2066.560 us; speedup vs baseline: 1.1437x; 1.1437x over previous
//
#include <hip/hip_runtime.h>

#define N_N 100000
#define N_E 1600000
#define N_G 256
#define F_IN 28
#define HEADS 4
#define CH 64
#define NEG 0.2f
#define LN_EPS 1e-5f

__device__ __forceinline__ float lrelu(float x) { return x > 0.f ? x : NEG * x; }

__device__ __forceinline__ float wsum(float v) {
#pragma unroll
  for (int o = 32; o > 0; o >>= 1) v += __shfl_xor(v, o, 64);
  return v;
}
__device__ __forceinline__ float wmax(float v) {
#pragma unroll
  for (int o = 32; o > 0; o >>= 1) v = fmaxf(v, __shfl_xor(v, o, 64));
  return v;
}
__device__ __forceinline__ int wsumi(int v) {
#pragma unroll
  for (int o = 32; o > 0; o >>= 1) v += __shfl_xor(v, o, 64);
  return v;
}

// ---------------- CSR build ----------------
__global__ __launch_bounds__(256) void k_deg(const int* __restrict__ dst, int* deg) {
  int e = blockIdx.x * 256 + threadIdx.x;
  if (e < N_E) atomicAdd(&deg[dst[e]], 1);
}

__global__ __launch_bounds__(256) void k_bsum(const int* __restrict__ deg, int* __restrict__ bsum) {
  __shared__ int l[4];
  int t = threadIdx.x;
  int i = blockIdx.x * 256 + t;
  int v = (i < N_N) ? deg[i] : 0;
  int s = wsumi(v);
  if ((t & 63) == 0) l[t >> 6] = s;
  __syncthreads();
  if (t == 0) bsum[blockIdx.x] = l[0] + l[1] + l[2] + l[3];
}

__global__ __launch_bounds__(512) void k_scanb(const int* __restrict__ bsum, int* __restrict__ bofs, int nb) {
  __shared__ int l[512];
  int t = threadIdx.x;
  int v = (t < nb) ? bsum[t] : 0;
  l[t] = v;
  __syncthreads();
  for (int o = 1; o < 512; o <<= 1) {
    int a = (t >= o) ? l[t - o] : 0;
    __syncthreads();
    l[t] += a;
    __syncthreads();
  }
  if (t < nb) bofs[t] = l[t] - v;  // exclusive
}

__global__ __launch_bounds__(256) void k_indptr(const int* __restrict__ deg, const int* __restrict__ bofs,
                                                int* __restrict__ indptr) {
  __shared__ int l[256];
  int t = threadIdx.x;
  int i = blockIdx.x * 256 + t;
  int v = (i < N_N) ? deg[i] : 0;
  l[t] = v;
  __syncthreads();
  for (int o = 1; o < 256; o <<= 1) {
    int a = (t >= o) ? l[t - o] : 0;
    __syncthreads();
    l[t] += a;
    __syncthreads();
  }
  if (i < N_N) indptr[i] = bofs[blockIdx.x] + l[t] - v;
  if (i == 0) indptr[N_N] = N_E;
}

__global__ __launch_bounds__(256) void k_copyfill(const int* __restrict__ indptr, int* __restrict__ fill) {
  int i = blockIdx.x * 256 + threadIdx.x;
  if (i < N_N) fill[i] = indptr[i];
}

__global__ __launch_bounds__(256) void k_scatter(const int* __restrict__ src, const int* __restrict__ dst,
                                                 int* fill, int* __restrict__ csr) {
  int e = blockIdx.x * 256 + threadIdx.x;
  if (e < N_E) {
    int d = dst[e];
    int p = atomicAdd(&fill[d], 1);
    csr[p] = src[e];
  }
}

// deterministic order within each bucket (sum order fixed across runs)
__global__ __launch_bounds__(256) void k_sort(const int* __restrict__ indptr, int* __restrict__ csr) {
  int i = blockIdx.x * 256 + threadIdx.x;
  if (i >= N_N) return;
  int b = indptr[i], e = indptr[i + 1];
  for (int j = b + 1; j < e; ++j) {
    int key = csr[j];
    int k = j - 1;
    while (k >= b && csr[k] > key) { csr[k + 1] = csr[k]; --k; }
    csr[k + 1] = key;
  }
}

// ---------------- attention logits: al = x @ (W_h a_h) ----------------
template <int F>
__global__ __launch_bounds__(256) void k_avec(const float* __restrict__ W, const float* __restrict__ as_,
                                              const float* __restrict__ ad_, float* __restrict__ wsv,
                                              float* __restrict__ wdv) {
  int idx = blockIdx.x * 256 + threadIdx.x;
  if (idx >= HEADS * F) return;
  int h = idx / F, f = idx % F;
  float s = 0.f, d = 0.f;
  for (int c = 0; c < 64; ++c) {
    float w = W[(h * F + f) * 64 + c];
    s = fmaf(w, as_[h * 64 + c], s);
    d = fmaf(w, ad_[h * 64 + c], d);
  }
  wsv[idx] = s;
  wdv[idx] = d;
}

template <int F>
__global__ __launch_bounds__(256) void k_al(const float* __restrict__ xin, const float* __restrict__ wsv,
                                            const float* __restrict__ wdv, float* __restrict__ al_s,
                                            float* __restrict__ al_d) {
  int wv = threadIdx.x >> 6, lane = threadIdx.x & 63;
  for (int i = blockIdx.x * 4 + wv; i < N_N; i += gridDim.x * 4) {
    float xv = (lane < F) ? xin[(size_t)i * F + lane] : 0.f;
#pragma unroll
    for (int h = 0; h < HEADS; ++h) {
      float ws_ = (lane < F) ? wsv[h * F + lane] : 0.f;
      float wd_ = (lane < F) ? wdv[h * F + lane] : 0.f;
      float ss = wsum(xv * ws_);
      float sd = wsum(xv * wd_);
      if (lane == 0) {
        al_s[i * 4 + h] = ss;
        al_d[i * 4 + h] = sd;
      }
    }
  }
}

// ---------------- fused GAT layer (wave per node, online softmax, chunked) ----
// out[i,c] = relu( bias[c] + 0.25 * sum_h sum_f aggF[i,h,f] * W[h,f,c] )
// aggF[i,h,f] = softmax-weighted sum over in-edges (incl self loop) of xin[s,f]
template <int F, int NW>
__global__ __launch_bounds__(64 * NW, 4) void k_gat(const float* __restrict__ xin, const int* __restrict__ indptr,
                                                    const int* __restrict__ csr, const float* __restrict__ al_s,
                                                    const float* __restrict__ al_d, const float* __restrict__ W,
                                                    const float* __restrict__ bias, float* __restrict__ xg) {
  __shared__ float wl[HEADS * F * 64];
  int t = threadIdx.x;
  for (int idx = t; idx < HEADS * F * 64; idx += 64 * NW) wl[idx] = W[idx];
  __syncthreads();
  int wv = t >> 6, lane = t & 63;
  for (int i = blockIdx.x * NW + wv; i < N_N; i += gridDim.x * NW) {
    int b = indptr[i], e = indptr[i + 1];
    float4 ad4 = *(const float4*)&al_d[i * 4];
    float4 as4 = *(const float4*)&al_s[i * 4];
    float es0 = lrelu(as4.x + ad4.x), es1 = lrelu(as4.y + ad4.y);
    float es2 = lrelu(as4.z + ad4.z), es3 = lrelu(as4.w + ad4.w);
    // running max per head (init = self-logit), accumulators, denominators
    float m0 = es0, m1 = es1, m2 = es2, m3 = es3;
    float xself = (lane < F) ? xin[(size_t)i * F + lane] : 0.f;
    float a0 = xself, a1 = xself, a2 = xself, a3 = xself;  // self weight exp(0)=1
    float pd0 = 0.f, pd1 = 0.f, pd2 = 0.f, pd3 = 0.f;
    for (int cb = b; cb < e; cb += 64) {
      int cnt = min(64, e - cb);
      bool act = (cb + lane) < e;
      int s = 0;
      float e0 = -1e30f, e1 = -1e30f, e2 = -1e30f, e3 = -1e30f;
      if (act) {
        s = csr[cb + lane];
        float4 a4 = *(const float4*)&al_s[s * 4];
        e0 = lrelu(a4.x + ad4.x);
        e1 = lrelu(a4.y + ad4.y);
        e2 = lrelu(a4.z + ad4.z);
        e3 = lrelu(a4.w + ad4.w);
      }
      // online rescale to new running max
      float n0 = fmaxf(m0, wmax(e0)), n1 = fmaxf(m1, wmax(e1));
      float n2 = fmaxf(m2, wmax(e2)), n3 = fmaxf(m3, wmax(e3));
      float sc0 = __expf(m0 - n0), sc1 = __expf(m1 - n1);
      float sc2 = __expf(m2 - n2), sc3 = __expf(m3 - n3);
      a0 *= sc0; a1 *= sc1; a2 *= sc2; a3 *= sc3;
      pd0 *= sc0; pd1 *= sc1; pd2 *= sc2; pd3 *= sc3;
      m0 = n0; m1 = n1; m2 = n2; m3 = n3;
      // lane-parallel weights
      float w0 = act ? __expf(e0 - m0) : 0.f;
      float w1 = act ? __expf(e1 - m1) : 0.f;
      float w2 = act ? __expf(e2 - m2) : 0.f;
      float w3 = act ? __expf(e3 - m3) : 0.f;
      pd0 += w0; pd1 += w1; pd2 += w2; pd3 += w3;
      // serial aggregation over chunk (weights broadcast via shfl)
      for (int je = 0; je < cnt; ++je) {
        int sj = __shfl(s, je, 64);
        float v0 = __shfl(w0, je, 64);
        float v1 = __shfl(w1, je, 64);
        float v2 = __shfl(w2, je, 64);
        float v3 = __shfl(w3, je, 64);
        float xvr = (lane < F) ? xin[(size_t)sj * F + lane] : 0.f;
        a0 = fmaf(v0, xvr, a0);
        a1 = fmaf(v1, xvr, a1);
        a2 = fmaf(v2, xvr, a2);
        a3 = fmaf(v3, xvr, a3);
      }
    }
    float dn0 = wsum(pd0) + __expf(es0 - m0);
    float dn1 = wsum(pd1) + __expf(es1 - m1);
    float dn2 = wsum(pd2) + __expf(es2 - m2);
    float dn3 = wsum(pd3) + __expf(es3 - m3);
    a0 /= dn0; a1 /= dn1; a2 /= dn2; a3 /= dn3;
    // apply W: o[c] = 0.25 * sum_h sum_f agg[h][f] * W[h,f,c]
    float o = 0.f;
#pragma unroll 4
    for (int f = 0; f < F; ++f) {
      float v0 = __shfl(a0, f, 64);
      float v1 = __shfl(a1, f, 64);
      float v2 = __shfl(a2, f, 64);
      float v3 = __shfl(a3, f, 64);
      o = fmaf(v0, wl[(0 * F + f) * 64 + lane], o);
      o = fmaf(v1, wl[(1 * F + f) * 64 + lane], o);
      o = fmaf(v2, wl[(2 * F + f) * 64 + lane], o);
      o = fmaf(v3, wl[(3 * F + f) * 64 + lane], o);
    }
    o = fmaxf(fmaf(o, 0.25f, bias[lane]), 0.f);
    xg[(size_t)i * 64 + lane] = o;
  }
}

// ---------------- fused GIN: agg + MLP + residual + LN (+ next-layer logits) --
template <int NW, bool FUSE_AL>
__global__ __launch_bounds__(64 * NW, 4) void k_gin(const int* __restrict__ indptr, const int* __restrict__ csr,
                                                    const float* __restrict__ xg, const float* __restrict__ w1,
                                                    const float* __restrict__ b1, const float* __restrict__ w2,
                                                    const float* __restrict__ b2, const float* __restrict__ lnw,
                                                    const float* __restrict__ lnb, float* __restrict__ xo,
                                                    const float* __restrict__ wsv, const float* __restrict__ wdv,
                                                    float* __restrict__ al_s, float* __restrict__ al_d) {
  __shared__ float w1l[4096], w2l[4096];
  int t = threadIdx.x;
  for (int idx = t; idx < 4096; idx += 64 * NW) {
    w1l[idx] = w1[idx];
    w2l[idx] = w2[idx];
  }
  __syncthreads();
  int wv = t >> 6, lane = t & 63;
  for (int i = blockIdx.x * NW + wv; i < N_N; i += gridDim.x * NW) {
    int b = indptr[i], e = indptr[i + 1];
    float xi = xg[(size_t)i * 64 + lane];
    float acc = xi;
    for (int j = b; j < e; ++j) acc += xg[(size_t)csr[j] * 64 + lane];
    float hv = b1[lane];
#pragma unroll 8
    for (int k = 0; k < 64; ++k) hv = fmaf(__shfl(acc, k, 64), w1l[k * 64 + lane], hv);
    hv = fmaxf(hv, 0.f);
    float ov = b2[lane];
#pragma unroll 8
    for (int k = 0; k < 64; ++k) ov = fmaf(__shfl(hv, k, 64), w2l[k * 64 + lane], ov);
    float res = xi + ov;
    float mu = wsum(res) * (1.f / 64.f);
    float d = res - mu;
    float var = wsum(d * d) * (1.f / 64.f);
    float xov = fmaf(d * rsqrtf(var + LN_EPS), lnw[lane], lnb[lane]);
    xo[(size_t)i * 64 + lane] = xov;
    if (FUSE_AL) {
#pragma unroll
      for (int h = 0; h < HEADS; ++h) {
        float ss = wsum(xov * wsv[h * 64 + lane]);
        float sd = wsum(xov * wdv[h * 64 + lane]);
        if (lane == 0) {
          al_s[i * 4 + h] = ss;
          al_d[i * 4 + h] = sd;
        }
      }
    }
  }
}

// ---------------- gate MLP ----------------
template <int NW>
__global__ __launch_bounds__(64 * NW, 4) void k_gatenn(const float* __restrict__ x2, const float* __restrict__ gw1,
                                                       const float* __restrict__ gb1, const float* __restrict__ gw2,
                                                       const float* __restrict__ gb2, float* __restrict__ gate) {
  __shared__ float wl[4096];
  __shared__ float g2l[64];
  int t = threadIdx.x;
  for (int idx = t; idx < 4096; idx += 64 * NW) wl[idx] = gw1[idx];
  if (t < 64) g2l[t] = gw2[t];
  __syncthreads();
  int wv = t >> 6, lane = t & 63;
  float gb2v = gb2[0];
  for (int i = blockIdx.x * NW + wv; i < N_N; i += gridDim.x * NW) {
    float vv = x2[(size_t)i * 64 + lane];
    float hv = gb1[lane];
#pragma unroll 8
    for (int k = 0; k < 64; ++k) hv = fmaf(__shfl(vv, k, 64), wl[k * 64 + lane], hv);
    hv = fmaxf(hv, 0.f);
    float g = wsum(hv * g2l[lane]);
    if (lane == 0) gate[i] = g + gb2v;
  }
}

// ---------------- graph ranges via counting ----------------
__global__ __launch_bounds__(256) void k_gcount(const int* __restrict__ batch, int* gcnt) {
  int i = blockIdx.x * 256 + threadIdx.x;
  if (i < N_N) atomicAdd(&gcnt[batch[i]], 1);
}

__global__ __launch_bounds__(256) void k_gptr(const int* __restrict__ gcnt, int* __restrict__ gptr) {
  __shared__ int l[256];
  int t = threadIdx.x;
  int v = gcnt[t];
  l[t] = v;
  __syncthreads();
  for (int o = 1; o < 256; o <<= 1) {
    int a = (t >= o) ? l[t - o] : 0;
    __syncthreads();
    l[t] += a;
    __syncthreads();
  }
  gptr[t] = l[t] - v;
  if (t == 255) gptr[256] = l[255];
}

// ---------------- global attention pool ----------------
__global__ __launch_bounds__(256) void k_pool(const int* __restrict__ gptr, const float* __restrict__ gate,
                                              const float* __restrict__ x2, float* __restrict__ pooled) {
  int g = blockIdx.x;
  int t = threadIdx.x, wv = t >> 6, lane = t & 63;
  __shared__ float red[256];
  int b = gptr[g], e = gptr[g + 1];
  if (b == e) {
    if (t < 64) pooled[g * 64 + t] = 0.f;
    return;
  }
  float m = -1e30f;
  for (int j = b + t; j < e; j += 256) m = fmaxf(m, gate[j]);
  m = wmax(m);
  if (lane == 0) red[wv] = m;
  __syncthreads();
  m = fmaxf(fmaxf(red[0], red[1]), fmaxf(red[2], red[3]));
  __syncthreads();
  float dn = 0.f;
  for (int j = b + t; j < e; j += 256) dn += __expf(gate[j] - m);
  dn = wsum(dn);
  if (lane == 0) red[wv] = dn;
  __syncthreads();
  dn = red[0] + red[1] + red[2] + red[3];
  __syncthreads();
  float acc = 0.f;
  for (int j = b + wv; j < e; j += 4) acc = fmaf(__expf(gate[j] - m), x2[(size_t)j * 64 + lane], acc);
  red[t] = acc;
  __syncthreads();
  if (t < 64) pooled[g * 64 + t] = (red[t] + red[t + 64] + red[t + 128] + red[t + 192]) / dn;
}

// ---------------- head MLP ----------------
__global__ __launch_bounds__(128) void k_head(const float* __restrict__ pooled, const float* __restrict__ l1w,
                                              const float* __restrict__ l1b, const float* __restrict__ lnfw,
                                              const float* __restrict__ lnfb, const float* __restrict__ l2w,
                                              const float* __restrict__ l2b, float* __restrict__ out) {
  int g = blockIdx.x, t = threadIdx.x;
  __shared__ float pl[64], zl[128], red[2];
  if (t < 64) pl[t] = pooled[g * 64 + t];
  __syncthreads();
  float y = l1b[t];
#pragma unroll 8
  for (int k = 0; k < 64; ++k) y = fmaf(pl[k], l1w[k * 128 + t], y);
  int wv = t >> 6, lane = t & 63;
  float s = wsum(y);
  if (lane == 0) red[wv] = s;
  __syncthreads();
  float mu = (red[0] + red[1]) * (1.f / 128.f);
  float d = y - mu;
  __syncthreads();
  s = wsum(d * d);
  if (lane == 0) red[wv] = s;
  __syncthreads();
  float var = (red[0] + red[1]) * (1.f / 128.f);
  float z = fmaxf(fmaf(d * rsqrtf(var + LN_EPS), lnfw[t], lnfb[t]), 0.f);
  zl[t] = z;
  __syncthreads();
  if (t < 6) {
    float o = l2b[t];
    for (int k = 0; k < 128; ++k) o = fmaf(zl[k], l2w[k * 6 + t], o);
    out[g * 6 + t] = o;
  }
}

extern "C" void kernel_launch(void* const* d_in, const int* in_sizes, int n_in,
                              void* d_out, int out_size, void* d_ws, size_t ws_size,
                              hipStream_t stream) {
  const float* x = (const float*)d_in[0];
  const int* src = (const int*)d_in[1];
  const int* dst = (const int*)d_in[2];
  const int* batch = (const int*)d_in[3];
  const float* W1 = (const float*)d_in[4];
  const float* a1s = (const float*)d_in[5];
  const float* a1d = (const float*)d_in[6];
  const float* bg1 = (const float*)d_in[7];
  const float* m1w1 = (const float*)d_in[8];
  const float* m1b1 = (const float*)d_in[9];
  const float* m1w2 = (const float*)d_in[10];
  const float* m1b2 = (const float*)d_in[11];
  const float* ln1w = (const float*)d_in[12];
  const float* ln1b = (const float*)d_in[13];
  const float* W2 = (const float*)d_in[14];
  const float* a2s = (const float*)d_in[15];
  const float* a2d = (const float*)d_in[16];
  const float* bg2 = (const float*)d_in[17];
  const float* m2w1 = (const float*)d_in[18];
  const float* m2b1 = (const float*)d_in[19];
  const float* m2w2 = (const float*)d_in[20];
  const float* m2b2 = (const float*)d_in[21];
  const float* ln2w = (const float*)d_in[22];
  const float* ln2b = (const float*)d_in[23];
  const float* gw1 = (const float*)d_in[24];
  const float* gb1 = (const float*)d_in[25];
  const float* gw2 = (const float*)d_in[26];
  const float* gb2 = (const float*)d_in[27];
  const float* l1w = (const float*)d_in[28];
  const float* l1b = (const float*)d_in[29];
  const float* lnfw = (const float*)d_in[30];
  const float* lnfb = (const float*)d_in[31];
  const float* l2w = (const float*)d_in[32];
  const float* l2b = (const float*)d_in[33];
  float* out = (float*)d_out;

  char* ws = (char*)d_ws;
  size_t off = 0;
  auto alloc = [&](size_t bytes) -> void* {
    void* p = ws + off;
    off += (bytes + 255) & ~(size_t)255;
    return p;
  };
  int* indptr = (int*)alloc((N_N + 1) * sizeof(int));
  int* fill = (int*)alloc(N_N * sizeof(int));       // also degree
  int* csr = (int*)alloc((size_t)N_E * sizeof(int));
  int* bsum = (int*)alloc(512 * sizeof(int));
  int* bofs = (int*)alloc(512 * sizeof(int));
  int* gcnt = (int*)alloc(257 * sizeof(int));
  int* gptr = (int*)alloc(257 * sizeof(int));
  float* wsv = (float*)alloc(HEADS * 64 * sizeof(float));
  float* wdv = (float*)alloc(HEADS * 64 * sizeof(float));
  float* al_s = (float*)alloc((size_t)N_N * 4 * sizeof(float));
  float* al_d = (float*)alloc((size_t)N_N * 4 * sizeof(float));
  float* gate = (float*)alloc((size_t)N_N * sizeof(float));
  float* pooled = (float*)alloc(N_G * 64 * sizeof(float));
  float* xg = (float*)alloc((size_t)N_N * 64 * sizeof(float));
  float* xv = (float*)alloc((size_t)N_N * 64 * sizeof(float));
  (void)ws_size; (void)n_in; (void)in_sizes; (void)out_size;

  const int NBE = (N_E + 255) / 256;
  const int NBN = (N_N + 255) / 256;  // 391

  hipMemsetAsync(fill, 0, (size_t)N_N * sizeof(int), stream);
  hipMemsetAsync(gcnt, 0, 257 * sizeof(int), stream);
  k_deg<<<NBE, 256, 0, stream>>>(dst, fill);
  k_bsum<<<NBN, 256, 0, stream>>>(fill, bsum);
  k_scanb<<<1, 512, 0, stream>>>(bsum, bofs, NBN);
  k_indptr<<<NBN, 256, 0, stream>>>(fill, bofs, indptr);
  k_copyfill<<<NBN, 256, 0, stream>>>(indptr, fill);
  k_scatter<<<NBE, 256, 0, stream>>>(src, dst, fill, csr);
  k_sort<<<NBN, 256, 0, stream>>>(indptr, csr);
  k_gcount<<<NBN, 256, 0, stream>>>(batch, gcnt);
  k_gptr<<<1, 256, 0, stream>>>(gcnt, gptr);

  // ---- layer 1 ----
  k_avec<F_IN><<<1, 256, 0, stream>>>(W1, a1s, a1d, wsv, wdv);
  k_al<F_IN><<<2048, 256, 0, stream>>>(x, wsv, wdv, al_s, al_d);
  k_gat<F_IN, 8><<<1024, 512, 0, stream>>>(x, indptr, csr, al_s, al_d, W1, bg1, xg);
  k_avec<CH><<<1, 256, 0, stream>>>(W2, a2s, a2d, wsv, wdv);  // layer-2 logit vectors
  k_gin<8, true><<<1024, 512, 0, stream>>>(indptr, csr, xg, m1w1, m1b1, m1w2, m1b2, ln1w, ln1b, xv,
                                           wsv, wdv, al_s, al_d);
  // ---- layer 2 ----
  k_gat<CH, 8><<<512, 512, 0, stream>>>(xv, indptr, csr, al_s, al_d, W2, bg2, xg);
  k_gin<8, false><<<1024, 512, 0, stream>>>(indptr, csr, xg, m2w1, m2b1, m2w2, m2b2, ln2w, ln2b, xv,
                                            wsv, wdv, al_s, al_d);
  // ---- pooling + head ----
  k_gatenn<8><<<1024, 512, 0, stream>>>(xv, gw1, gb1, gw2, gb2, gate);
  k_pool<<<N_G, 256, 0, stream>>>(gptr, gate, xv, pooled);
  k_head<<<N_G, 128, 0, stream>>>(pooled, l1w, l1b, lnfw, lnfb, l2w, l2b, out);
}

// Round 3
// 1771.718 us; speedup vs baseline: 1.3340x; 1.1664x over previous
//
#include <hip/hip_runtime.h>

#define N_N 100000
#define N_E 1600000
#define N_G 256
#define F_IN 28
#define HEADS 4
#define CH 64
#define NEG 0.2f
#define LN_EPS 1e-5f

__device__ __forceinline__ float lrelu(float x) { return x > 0.f ? x : NEG * x; }

__device__ __forceinline__ float wsum(float v) {
#pragma unroll
  for (int o = 32; o > 0; o >>= 1) v += __shfl_xor(v, o, 64);
  return v;
}
__device__ __forceinline__ float wmax(float v) {
#pragma unroll
  for (int o = 32; o > 0; o >>= 1) v = fmaxf(v, __shfl_xor(v, o, 64));
  return v;
}
__device__ __forceinline__ int wsumi(int v) {
#pragma unroll
  for (int o = 32; o > 0; o >>= 1) v += __shfl_xor(v, o, 64);
  return v;
}

// ---------------- CSR build ----------------
__global__ __launch_bounds__(256) void k_deg(const int* __restrict__ dst, int* deg) {
  int e = blockIdx.x * 256 + threadIdx.x;
  if (e < N_E) atomicAdd(&deg[dst[e]], 1);
}

__global__ __launch_bounds__(256) void k_bsum(const int* __restrict__ deg, int* __restrict__ bsum) {
  __shared__ int l[4];
  int t = threadIdx.x;
  int i = blockIdx.x * 256 + t;
  int v = (i < N_N) ? deg[i] : 0;
  int s = wsumi(v);
  if ((t & 63) == 0) l[t >> 6] = s;
  __syncthreads();
  if (t == 0) bsum[blockIdx.x] = l[0] + l[1] + l[2] + l[3];
}

__global__ __launch_bounds__(512) void k_scanb(const int* __restrict__ bsum, int* __restrict__ bofs, int nb) {
  __shared__ int l[512];
  int t = threadIdx.x;
  int v = (t < nb) ? bsum[t] : 0;
  l[t] = v;
  __syncthreads();
  for (int o = 1; o < 512; o <<= 1) {
    int a = (t >= o) ? l[t - o] : 0;
    __syncthreads();
    l[t] += a;
    __syncthreads();
  }
  if (t < nb) bofs[t] = l[t] - v;  // exclusive
}

__global__ __launch_bounds__(256) void k_indptr(const int* __restrict__ deg, const int* __restrict__ bofs,
                                                int* __restrict__ indptr) {
  __shared__ int l[256];
  int t = threadIdx.x;
  int i = blockIdx.x * 256 + t;
  int v = (i < N_N) ? deg[i] : 0;
  l[t] = v;
  __syncthreads();
  for (int o = 1; o < 256; o <<= 1) {
    int a = (t >= o) ? l[t - o] : 0;
    __syncthreads();
    l[t] += a;
    __syncthreads();
  }
  if (i < N_N) indptr[i] = bofs[blockIdx.x] + l[t] - v;
  if (i == 0) indptr[N_N] = N_E;
}

__global__ __launch_bounds__(256) void k_copyfill(const int* __restrict__ indptr, int* __restrict__ fill) {
  int i = blockIdx.x * 256 + threadIdx.x;
  if (i < N_N) fill[i] = indptr[i];
}

__global__ __launch_bounds__(256) void k_scatter(const int* __restrict__ src, const int* __restrict__ dst,
                                                 int* fill, int* __restrict__ csr) {
  int e = blockIdx.x * 256 + threadIdx.x;
  if (e < N_E) {
    int d = dst[e];
    int p = atomicAdd(&fill[d], 1);
    csr[p] = src[e];
  }
}

// deterministic order within each bucket (sum order fixed across runs)
__global__ __launch_bounds__(256) void k_sort(const int* __restrict__ indptr, int* __restrict__ csr) {
  int i = blockIdx.x * 256 + threadIdx.x;
  if (i >= N_N) return;
  int b = indptr[i], e = indptr[i + 1];
  for (int j = b + 1; j < e; ++j) {
    int key = csr[j];
    int k = j - 1;
    while (k >= b && csr[k] > key) { csr[k + 1] = csr[k]; --k; }
    csr[k + 1] = key;
  }
}

// ---------------- attention logits: al = x @ (W_h a_h) ----------------
template <int F>
__global__ __launch_bounds__(256) void k_avec(const float* __restrict__ W, const float* __restrict__ as_,
                                              const float* __restrict__ ad_, float* __restrict__ wsv,
                                              float* __restrict__ wdv) {
  int idx = blockIdx.x * 256 + threadIdx.x;
  if (idx >= HEADS * F) return;
  int h = idx / F, f = idx % F;
  float s = 0.f, d = 0.f;
  for (int c = 0; c < 64; ++c) {
    float w = W[(h * F + f) * 64 + c];
    s = fmaf(w, as_[h * 64 + c], s);
    d = fmaf(w, ad_[h * 64 + c], d);
  }
  wsv[idx] = s;
  wdv[idx] = d;
}

template <int F>
__global__ __launch_bounds__(256) void k_al(const float* __restrict__ xin, const float* __restrict__ wsv,
                                            const float* __restrict__ wdv, float* __restrict__ al_s,
                                            float* __restrict__ al_d) {
  int wv = threadIdx.x >> 6, lane = threadIdx.x & 63;
  for (int i = blockIdx.x * 4 + wv; i < N_N; i += gridDim.x * 4) {
    float xv = (lane < F) ? xin[(size_t)i * F + lane] : 0.f;
#pragma unroll
    for (int h = 0; h < HEADS; ++h) {
      float ws_ = (lane < F) ? wsv[h * F + lane] : 0.f;
      float wd_ = (lane < F) ? wdv[h * F + lane] : 0.f;
      float ss = wsum(xv * ws_);
      float sd = wsum(xv * wd_);
      if (lane == 0) {
        al_s[i * 4 + h] = ss;
        al_d[i * 4 + h] = sd;
      }
    }
  }
}

// ---------------- fused GAT layer (wave per node, online softmax, chunked,
//                  LDS-stashed weights, unroll-8 gather pipeline) ----------
// out[i,c] = relu( bias[c] + 0.25 * sum_h sum_f aggF[i,h,f] * W[h,f,c] )
template <int F, int NW>
__global__ __launch_bounds__(64 * NW, 4) void k_gat(const float* __restrict__ xin, const int* __restrict__ indptr,
                                                    const int* __restrict__ csr, const float* __restrict__ al_s,
                                                    const float* __restrict__ al_d, const float* __restrict__ W,
                                                    const float* __restrict__ bias, float* __restrict__ xg) {
  __shared__ float wl[HEADS * F * 64];
  __shared__ int s_idx[NW][64];
  __shared__ float4 s_w[NW][64];
  int t = threadIdx.x;
  for (int idx = t; idx < HEADS * F * 64; idx += 64 * NW) wl[idx] = W[idx];
  __syncthreads();
  int wv = t >> 6, lane = t & 63;
  int lanef = lane & 31;  // used by dual-half (F=28) path
  int half = lane >> 5;
  for (int i = blockIdx.x * NW + wv; i < N_N; i += gridDim.x * NW) {
    int b = indptr[i], e = indptr[i + 1];
    float4 ad4 = *(const float4*)&al_d[i * 4];
    float4 as4 = *(const float4*)&al_s[i * 4];
    float es0 = lrelu(as4.x + ad4.x), es1 = lrelu(as4.y + ad4.y);
    float es2 = lrelu(as4.z + ad4.z), es3 = lrelu(as4.w + ad4.w);
    // running max per head (init = self-logit), accumulators, denominators
    float m0 = es0, m1 = es1, m2 = es2, m3 = es3;
    float xself = (lane < F) ? xin[(size_t)i * F + lane] : 0.f;
    float a0 = xself, a1 = xself, a2 = xself, a3 = xself;  // self weight exp(0)=1
    if (F == F_IN && half) { a0 = 0.f; a1 = 0.f; a2 = 0.f; a3 = 0.f; }
    float pd0 = 0.f, pd1 = 0.f, pd2 = 0.f, pd3 = 0.f;
    for (int cb = b; cb < e; cb += 64) {
      int cnt = min(64, e - cb);
      bool act = (cb + lane) < e;
      int s = 0;
      float e0 = -1e30f, e1 = -1e30f, e2 = -1e30f, e3 = -1e30f;
      if (act) {
        s = csr[cb + lane];
        float4 a4 = *(const float4*)&al_s[s * 4];
        e0 = lrelu(a4.x + ad4.x);
        e1 = lrelu(a4.y + ad4.y);
        e2 = lrelu(a4.z + ad4.z);
        e3 = lrelu(a4.w + ad4.w);
      }
      // online rescale to new running max
      float n0 = fmaxf(m0, wmax(e0)), n1 = fmaxf(m1, wmax(e1));
      float n2 = fmaxf(m2, wmax(e2)), n3 = fmaxf(m3, wmax(e3));
      float sc0 = __expf(m0 - n0), sc1 = __expf(m1 - n1);
      float sc2 = __expf(m2 - n2), sc3 = __expf(m3 - n3);
      a0 *= sc0; a1 *= sc1; a2 *= sc2; a3 *= sc3;
      pd0 *= sc0; pd1 *= sc1; pd2 *= sc2; pd3 *= sc3;
      m0 = n0; m1 = n1; m2 = n2; m3 = n3;
      // lane-parallel weights
      float w0 = act ? __expf(e0 - m0) : 0.f;
      float w1 = act ? __expf(e1 - m1) : 0.f;
      float w2 = act ? __expf(e2 - m2) : 0.f;
      float w3 = act ? __expf(e3 - m3) : 0.f;
      pd0 += w0; pd1 += w1; pd2 += w2; pd3 += w3;
      // stash indices + weights to wave-private LDS (inactive lanes: s=0, w=0)
      s_idx[wv][lane] = s;
      s_w[wv][lane] = make_float4(w0, w1, w2, w3);
      __builtin_amdgcn_s_waitcnt(0);  // lgkmcnt(0): LDS writes visible to own wave
      if (F == F_IN) {
        // dual-edge: low half handles even edges, high half odd edges
        for (int je = 0; je < cnt; je += 16) {
          int sj[8];
#pragma unroll
          for (int u = 0; u < 8; ++u) sj[u] = s_idx[wv][je + 2 * u + half];
          float xr[8];
#pragma unroll
          for (int u = 0; u < 8; ++u)
            xr[u] = (lanef < F_IN) ? xin[(size_t)sj[u] * F_IN + lanef] : 0.f;
#pragma unroll
          for (int u = 0; u < 8; ++u) {
            float4 w4 = s_w[wv][je + 2 * u + half];
            a0 = fmaf(w4.x, xr[u], a0);
            a1 = fmaf(w4.y, xr[u], a1);
            a2 = fmaf(w4.z, xr[u], a2);
            a3 = fmaf(w4.w, xr[u], a3);
          }
        }
      } else {
        for (int je = 0; je < cnt; je += 8) {
          int sj[8];
#pragma unroll
          for (int u = 0; u < 8; ++u) sj[u] = s_idx[wv][je + u];
          float xr[8];
#pragma unroll
          for (int u = 0; u < 8; ++u) xr[u] = xin[(size_t)sj[u] * F + lane];
#pragma unroll
          for (int u = 0; u < 8; ++u) {
            float4 w4 = s_w[wv][je + u];
            a0 = fmaf(w4.x, xr[u], a0);
            a1 = fmaf(w4.y, xr[u], a1);
            a2 = fmaf(w4.z, xr[u], a2);
            a3 = fmaf(w4.w, xr[u], a3);
          }
        }
      }
    }
    if (F == F_IN) {
      // combine halves (lanes 0..27 get totals)
      a0 += __shfl_xor(a0, 32, 64);
      a1 += __shfl_xor(a1, 32, 64);
      a2 += __shfl_xor(a2, 32, 64);
      a3 += __shfl_xor(a3, 32, 64);
    }
    float dn0 = wsum(pd0) + __expf(es0 - m0);
    float dn1 = wsum(pd1) + __expf(es1 - m1);
    float dn2 = wsum(pd2) + __expf(es2 - m2);
    float dn3 = wsum(pd3) + __expf(es3 - m3);
    a0 /= dn0; a1 /= dn1; a2 /= dn2; a3 /= dn3;
    // apply W: o[c] = 0.25 * sum_h sum_f agg[h][f] * W[h,f,c]
    float o = 0.f;
#pragma unroll 4
    for (int f = 0; f < F; ++f) {
      float v0 = __shfl(a0, f, 64);
      float v1 = __shfl(a1, f, 64);
      float v2 = __shfl(a2, f, 64);
      float v3 = __shfl(a3, f, 64);
      o = fmaf(v0, wl[(0 * F + f) * 64 + lane], o);
      o = fmaf(v1, wl[(1 * F + f) * 64 + lane], o);
      o = fmaf(v2, wl[(2 * F + f) * 64 + lane], o);
      o = fmaf(v3, wl[(3 * F + f) * 64 + lane], o);
    }
    o = fmaxf(fmaf(o, 0.25f, bias[lane]), 0.f);
    xg[(size_t)i * 64 + lane] = o;
  }
}

// ---------------- fused GIN: agg + MLP + residual + LN (+ next-layer logits) --
template <int NW, bool FUSE_AL>
__global__ __launch_bounds__(64 * NW, 4) void k_gin(const int* __restrict__ indptr, const int* __restrict__ csr,
                                                    const float* __restrict__ xg, const float* __restrict__ w1,
                                                    const float* __restrict__ b1, const float* __restrict__ w2,
                                                    const float* __restrict__ b2, const float* __restrict__ lnw,
                                                    const float* __restrict__ lnb, float* __restrict__ xo,
                                                    const float* __restrict__ wsv, const float* __restrict__ wdv,
                                                    float* __restrict__ al_s, float* __restrict__ al_d) {
  __shared__ float w1l[4096], w2l[4096];
  int t = threadIdx.x;
  for (int idx = t; idx < 4096; idx += 64 * NW) {
    w1l[idx] = w1[idx];
    w2l[idx] = w2[idx];
  }
  __syncthreads();
  int wv = t >> 6, lane = t & 63;
  for (int i = blockIdx.x * NW + wv; i < N_N; i += gridDim.x * NW) {
    int b = indptr[i], e = indptr[i + 1];
    float xi = xg[(size_t)i * 64 + lane];
    float acc = xi;
    for (int j = b; j < e; j += 8) {
      int cj[8];
      bool mk[8];
#pragma unroll
      for (int u = 0; u < 8; ++u) {
        int jj = min(j + u, e - 1);
        cj[u] = csr[jj];
        mk[u] = (j + u) < e;
      }
      float v[8];
#pragma unroll
      for (int u = 0; u < 8; ++u) v[u] = xg[(size_t)cj[u] * 64 + lane];
#pragma unroll
      for (int u = 0; u < 8; ++u) acc += mk[u] ? v[u] : 0.f;
    }
    float hv = b1[lane];
#pragma unroll 8
    for (int k = 0; k < 64; ++k) hv = fmaf(__shfl(acc, k, 64), w1l[k * 64 + lane], hv);
    hv = fmaxf(hv, 0.f);
    float ov = b2[lane];
#pragma unroll 8
    for (int k = 0; k < 64; ++k) ov = fmaf(__shfl(hv, k, 64), w2l[k * 64 + lane], ov);
    float res = xi + ov;
    float mu = wsum(res) * (1.f / 64.f);
    float d = res - mu;
    float var = wsum(d * d) * (1.f / 64.f);
    float xov = fmaf(d * rsqrtf(var + LN_EPS), lnw[lane], lnb[lane]);
    xo[(size_t)i * 64 + lane] = xov;
    if (FUSE_AL) {
#pragma unroll
      for (int h = 0; h < HEADS; ++h) {
        float ss = wsum(xov * wsv[h * 64 + lane]);
        float sd = wsum(xov * wdv[h * 64 + lane]);
        if (lane == 0) {
          al_s[i * 4 + h] = ss;
          al_d[i * 4 + h] = sd;
        }
      }
    }
  }
}

// ---------------- gate MLP ----------------
template <int NW>
__global__ __launch_bounds__(64 * NW, 4) void k_gatenn(const float* __restrict__ x2, const float* __restrict__ gw1,
                                                       const float* __restrict__ gb1, const float* __restrict__ gw2,
                                                       const float* __restrict__ gb2, float* __restrict__ gate) {
  __shared__ float wl[4096];
  __shared__ float g2l[64];
  int t = threadIdx.x;
  for (int idx = t; idx < 4096; idx += 64 * NW) wl[idx] = gw1[idx];
  if (t < 64) g2l[t] = gw2[t];
  __syncthreads();
  int wv = t >> 6, lane = t & 63;
  float gb2v = gb2[0];
  for (int i = blockIdx.x * NW + wv; i < N_N; i += gridDim.x * NW) {
    float vv = x2[(size_t)i * 64 + lane];
    float hv = gb1[lane];
#pragma unroll 8
    for (int k = 0; k < 64; ++k) hv = fmaf(__shfl(vv, k, 64), wl[k * 64 + lane], hv);
    hv = fmaxf(hv, 0.f);
    float g = wsum(hv * g2l[lane]);
    if (lane == 0) gate[i] = g + gb2v;
  }
}

// ---------------- graph ranges via counting ----------------
__global__ __launch_bounds__(256) void k_gcount(const int* __restrict__ batch, int* gcnt) {
  int i = blockIdx.x * 256 + threadIdx.x;
  if (i < N_N) atomicAdd(&gcnt[batch[i]], 1);
}

__global__ __launch_bounds__(256) void k_gptr(const int* __restrict__ gcnt, int* __restrict__ gptr) {
  __shared__ int l[256];
  int t = threadIdx.x;
  int v = gcnt[t];
  l[t] = v;
  __syncthreads();
  for (int o = 1; o < 256; o <<= 1) {
    int a = (t >= o) ? l[t - o] : 0;
    __syncthreads();
    l[t] += a;
    __syncthreads();
  }
  gptr[t] = l[t] - v;
  if (t == 255) gptr[256] = l[255];
}

// ---------------- global attention pool ----------------
__global__ __launch_bounds__(256) void k_pool(const int* __restrict__ gptr, const float* __restrict__ gate,
                                              const float* __restrict__ x2, float* __restrict__ pooled) {
  int g = blockIdx.x;
  int t = threadIdx.x, wv = t >> 6, lane = t & 63;
  __shared__ float red[256];
  int b = gptr[g], e = gptr[g + 1];
  if (b == e) {
    if (t < 64) pooled[g * 64 + t] = 0.f;
    return;
  }
  float m = -1e30f;
  for (int j = b + t; j < e; j += 256) m = fmaxf(m, gate[j]);
  m = wmax(m);
  if (lane == 0) red[wv] = m;
  __syncthreads();
  m = fmaxf(fmaxf(red[0], red[1]), fmaxf(red[2], red[3]));
  __syncthreads();
  float dn = 0.f;
  for (int j = b + t; j < e; j += 256) dn += __expf(gate[j] - m);
  dn = wsum(dn);
  if (lane == 0) red[wv] = dn;
  __syncthreads();
  dn = red[0] + red[1] + red[2] + red[3];
  __syncthreads();
  float acc = 0.f;
  for (int j = b + wv; j < e; j += 4) acc = fmaf(__expf(gate[j] - m), x2[(size_t)j * 64 + lane], acc);
  red[t] = acc;
  __syncthreads();
  if (t < 64) pooled[g * 64 + t] = (red[t] + red[t + 64] + red[t + 128] + red[t + 192]) / dn;
}

// ---------------- head MLP ----------------
__global__ __launch_bounds__(128) void k_head(const float* __restrict__ pooled, const float* __restrict__ l1w,
                                              const float* __restrict__ l1b, const float* __restrict__ lnfw,
                                              const float* __restrict__ lnfb, const float* __restrict__ l2w,
                                              const float* __restrict__ l2b, float* __restrict__ out) {
  int g = blockIdx.x, t = threadIdx.x;
  __shared__ float pl[64], zl[128], red[2];
  if (t < 64) pl[t] = pooled[g * 64 + t];
  __syncthreads();
  float y = l1b[t];
#pragma unroll 8
  for (int k = 0; k < 64; ++k) y = fmaf(pl[k], l1w[k * 128 + t], y);
  int wv = t >> 6, lane = t & 63;
  float s = wsum(y);
  if (lane == 0) red[wv] = s;
  __syncthreads();
  float mu = (red[0] + red[1]) * (1.f / 128.f);
  float d = y - mu;
  __syncthreads();
  s = wsum(d * d);
  if (lane == 0) red[wv] = s;
  __syncthreads();
  float var = (red[0] + red[1]) * (1.f / 128.f);
  float z = fmaxf(fmaf(d * rsqrtf(var + LN_EPS), lnfw[t], lnfb[t]), 0.f);
  zl[t] = z;
  __syncthreads();
  if (t < 6) {
    float o = l2b[t];
    for (int k = 0; k < 128; ++k) o = fmaf(zl[k], l2w[k * 6 + t], o);
    out[g * 6 + t] = o;
  }
}

extern "C" void kernel_launch(void* const* d_in, const int* in_sizes, int n_in,
                              void* d_out, int out_size, void* d_ws, size_t ws_size,
                              hipStream_t stream) {
  const float* x = (const float*)d_in[0];
  const int* src = (const int*)d_in[1];
  const int* dst = (const int*)d_in[2];
  const int* batch = (const int*)d_in[3];
  const float* W1 = (const float*)d_in[4];
  const float* a1s = (const float*)d_in[5];
  const float* a1d = (const float*)d_in[6];
  const float* bg1 = (const float*)d_in[7];
  const float* m1w1 = (const float*)d_in[8];
  const float* m1b1 = (const float*)d_in[9];
  const float* m1w2 = (const float*)d_in[10];
  const float* m1b2 = (const float*)d_in[11];
  const float* ln1w = (const float*)d_in[12];
  const float* ln1b = (const float*)d_in[13];
  const float* W2 = (const float*)d_in[14];
  const float* a2s = (const float*)d_in[15];
  const float* a2d = (const float*)d_in[16];
  const float* bg2 = (const float*)d_in[17];
  const float* m2w1 = (const float*)d_in[18];
  const float* m2b1 = (const float*)d_in[19];
  const float* m2w2 = (const float*)d_in[20];
  const float* m2b2 = (const float*)d_in[21];
  const float* ln2w = (const float*)d_in[22];
  const float* ln2b = (const float*)d_in[23];
  const float* gw1 = (const float*)d_in[24];
  const float* gb1 = (const float*)d_in[25];
  const float* gw2 = (const float*)d_in[26];
  const float* gb2 = (const float*)d_in[27];
  const float* l1w = (const float*)d_in[28];
  const float* l1b = (const float*)d_in[29];
  const float* lnfw = (const float*)d_in[30];
  const float* lnfb = (const float*)d_in[31];
  const float* l2w = (const float*)d_in[32];
  const float* l2b = (const float*)d_in[33];
  float* out = (float*)d_out;

  char* ws = (char*)d_ws;
  size_t off = 0;
  auto alloc = [&](size_t bytes) -> void* {
    void* p = ws + off;
    off += (bytes + 255) & ~(size_t)255;
    return p;
  };
  int* indptr = (int*)alloc((N_N + 1) * sizeof(int));
  int* fill = (int*)alloc(N_N * sizeof(int));       // also degree
  int* csr = (int*)alloc((size_t)N_E * sizeof(int));
  int* bsum = (int*)alloc(512 * sizeof(int));
  int* bofs = (int*)alloc(512 * sizeof(int));
  int* gcnt = (int*)alloc(257 * sizeof(int));
  int* gptr = (int*)alloc(257 * sizeof(int));
  float* wsv = (float*)alloc(HEADS * 64 * sizeof(float));
  float* wdv = (float*)alloc(HEADS * 64 * sizeof(float));
  float* al_s = (float*)alloc((size_t)N_N * 4 * sizeof(float));
  float* al_d = (float*)alloc((size_t)N_N * 4 * sizeof(float));
  float* gate = (float*)alloc((size_t)N_N * sizeof(float));
  float* pooled = (float*)alloc(N_G * 64 * sizeof(float));
  float* xg = (float*)alloc((size_t)N_N * 64 * sizeof(float));
  float* xv = (float*)alloc((size_t)N_N * 64 * sizeof(float));
  (void)ws_size; (void)n_in; (void)in_sizes; (void)out_size;

  const int NBE = (N_E + 255) / 256;
  const int NBN = (N_N + 255) / 256;  // 391

  hipMemsetAsync(fill, 0, (size_t)N_N * sizeof(int), stream);
  hipMemsetAsync(gcnt, 0, 257 * sizeof(int), stream);
  k_deg<<<NBE, 256, 0, stream>>>(dst, fill);
  k_bsum<<<NBN, 256, 0, stream>>>(fill, bsum);
  k_scanb<<<1, 512, 0, stream>>>(bsum, bofs, NBN);
  k_indptr<<<NBN, 256, 0, stream>>>(fill, bofs, indptr);
  k_copyfill<<<NBN, 256, 0, stream>>>(indptr, fill);
  k_scatter<<<NBE, 256, 0, stream>>>(src, dst, fill, csr);
  k_sort<<<NBN, 256, 0, stream>>>(indptr, csr);
  k_gcount<<<NBN, 256, 0, stream>>>(batch, gcnt);
  k_gptr<<<1, 256, 0, stream>>>(gcnt, gptr);

  // ---- layer 1 ----
  k_avec<F_IN><<<1, 256, 0, stream>>>(W1, a1s, a1d, wsv, wdv);
  k_al<F_IN><<<2048, 256, 0, stream>>>(x, wsv, wdv, al_s, al_d);
  k_gat<F_IN, 8><<<2048, 512, 0, stream>>>(x, indptr, csr, al_s, al_d, W1, bg1, xg);
  k_avec<CH><<<1, 256, 0, stream>>>(W2, a2s, a2d, wsv, wdv);  // layer-2 logit vectors
  k_gin<8, true><<<2048, 512, 0, stream>>>(indptr, csr, xg, m1w1, m1b1, m1w2, m1b2, ln1w, ln1b, xv,
                                           wsv, wdv, al_s, al_d);
  // ---- layer 2 ----
  k_gat<CH, 8><<<2048, 512, 0, stream>>>(xv, indptr, csr, al_s, al_d, W2, bg2, xg);
  k_gin<8, false><<<2048, 512, 0, stream>>>(indptr, csr, xg, m2w1, m2b1, m2w2, m2b2, ln2w, ln2b, xv,
                                            wsv, wdv, al_s, al_d);
  // ---- pooling + head ----
  k_gatenn<8><<<2048, 512, 0, stream>>>(xv, gw1, gb1, gw2, gb2, gate);
  k_pool<<<N_G, 256, 0, stream>>>(gptr, gate, xv, pooled);
  k_head<<<N_G, 128, 0, stream>>>(pooled, l1w, l1b, lnfw, lnfb, l2w, l2b, out);
}